// Round 1
// 4615.334 us; speedup vs baseline: 1.4360x; 1.4360x over previous
//
// LSTMDecoder on MI355X — round 8: attack load-latency serialization (VGPR=32 symptom).
//
// Journal:
// * R2: multi-kernel PASSED 0.0117 @ 9763us. R3-R6: barrier/coop designs failed -> abandoned.
// * R7 (prev best, 6627us): 3 kernels/step (kA fused gates2+gates1, kB e-dots+hw, kC softmax+o_t).
//   rocprof: gemm8 = 143us, VGPR_Count=32 (!), MfmaUtil=4.7%, VALUBusy=4.7%, 400 GB/s.
//   Diagnosis: compiler allocated minimal VGPRs -> per-MFMA register reuse -> vmcnt(0) before
//   every MFMA -> full ~500cy load latency exposed each k-step. Same pattern in kA's gseg
//   (which also runs at 1 wave/SIMD on half the CUs -> zero TLP to hide it).
// * R8 (this): depth-4 register-rotated prefetch in ALL mfma k-loops (gseg_pf / gemm8), static
//   buffer indices, launch_bounds raised to give the regalloc room ((256,1) kA, (256,2) gemm8/kB).
//   kC: 256 blocks x 128 thr, shuffle-reduce softmax, 4 split acc chains + unroll 8 gather.
//   kB e-dots explicitly vectorized. Accumulation order preserved -> numerics identical.
//
// Numerics: fp16 MFMA fp32-acc, c-state fp32, fp32 h2 copy for e-dot (proven 0.0117 schedule).

#include <hip/hip_runtime.h>

static constexpr int Bn = 64, Ln = 128, Tn = 48, En = 512, HEn = 1024, Hn = 1024, Gn = 4096;

typedef _Float16 h16;
typedef __attribute__((ext_vector_type(8))) _Float16 h16x8;
typedef __attribute__((ext_vector_type(2))) _Float16 h16x2;
typedef __attribute__((ext_vector_type(4))) float f32x4;

__device__ __forceinline__ float sigf(float x){ return 1.f / (1.f + expf(-x)); }

// ---------------- fp32 -> fp16 conversion ----------------
__global__ void cvt2(const float* __restrict__ in, h16x2* __restrict__ out, int n2){
  int i = blockIdx.x * blockDim.x + threadIdx.x;
  int stride = gridDim.x * blockDim.x;
  for (; i < n2; i += stride){
    float2 v = reinterpret_cast<const float2*>(in)[i];
    h16x2 o; o.x = (h16)v.x; o.y = (h16)v.y;
    out[i] = o;
  }
}

// ---------------- state init ----------------
__global__ void init_state(const float* __restrict__ h1i, const float* __restrict__ c1i,
                           const float* __restrict__ h2i, const float* __restrict__ c2i,
                           h16* __restrict__ h1a, float* __restrict__ c1,
                           h16* __restrict__ h2a, float* __restrict__ c2,
                           float* __restrict__ h2f, h16* __restrict__ oh){
  int i = blockIdx.x * blockDim.x + threadIdx.x;
  if (i < Bn * Hn){
    h1a[i] = (h16)h1i[i]; c1[i] = c1i[i];
    h2a[i] = (h16)h2i[i]; c2[i] = c2i[i];
    h2f[i] = h2i[i];
    oh[i] = (h16)0.f;
  }
}

// ---------------- gemm8: 64 rows x 128 cols / block, depth-4 prefetched k-loop ----------------
struct GBuf { h16x8 a; h16x8 b[8]; };

__device__ __forceinline__ void gld(GBuf& g, const h16* __restrict__ arow,
                                    const h16* __restrict__ brow, int ldb, int k){
  g.a = *reinterpret_cast<const h16x8*>(arow + k);
  #pragma unroll
  for (int nt = 0; nt < 8; nt++)
    g.b[nt] = *reinterpret_cast<const h16x8*>(brow + (size_t)nt * 16 * ldb + k);
}
__device__ __forceinline__ void gmm(const GBuf& g, f32x4* acc){
  #pragma unroll
  for (int nt = 0; nt < 8; nt++)
    acc[nt] = __builtin_amdgcn_mfma_f32_16x16x32_f16(g.a, g.b[nt], acc[nt], 0, 0, 0);
}

__global__ __launch_bounds__(256, 2) void gemm8(
    const h16* __restrict__ A, int lda,
    const h16* __restrict__ Bw, int ldb,
    const float* __restrict__ bias0, const float* __restrict__ bias1,
    float* __restrict__ outF, h16* __restrict__ outH, int ldc, int K)
{
  int w = threadIdx.x >> 6, lane = threadIdx.x & 63;
  int la = lane & 15, q = lane >> 4;
  int m0 = blockIdx.x * 64 + w * 16;
  int n0 = blockIdx.y * 128;
  f32x4 acc[8];
  #pragma unroll
  for (int i = 0; i < 8; i++) acc[i] = (f32x4){0.f, 0.f, 0.f, 0.f};
  const h16* arow = A + (size_t)(m0 + la) * lda + q * 8;
  const h16* brow = Bw + (size_t)(n0 + la) * ldb + q * 8;
  int nk = K / 32;   // K in {512, 1024} -> nk in {16, 32}, multiple of 4
  GBuf g0, g1, g2, g3;
  gld(g0, arow, brow, ldb, 0);
  gld(g1, arow, brow, ldb, 32);
  gld(g2, arow, brow, ldb, 64);
  gld(g3, arow, brow, ldb, 96);
  #pragma unroll 1
  for (int s = 0; s + 4 < nk; s += 4){
    gmm(g0, acc); gld(g0, arow, brow, ldb, (s + 4) * 32);
    gmm(g1, acc); gld(g1, arow, brow, ldb, (s + 5) * 32);
    gmm(g2, acc); gld(g2, arow, brow, ldb, (s + 6) * 32);
    gmm(g3, acc); gld(g3, arow, brow, ldb, (s + 7) * 32);
  }
  gmm(g0, acc); gmm(g1, acc); gmm(g2, acc); gmm(g3, acc);

  int mrow = m0 + q * 4;
  #pragma unroll
  for (int nt = 0; nt < 8; nt++){
    int n = n0 + nt * 16 + la;
    float bs = (bias0 ? bias0[n] : 0.f) + (bias1 ? bias1[n] : 0.f);
    #pragma unroll
    for (int r = 0; r < 4; r++){
      float v = acc[nt][r] + bs;
      size_t off = (size_t)(mrow + r) * ldc + n;
      if (outF) outF[off] = v;
      else      outH[off] = (h16)v;
    }
  }
}

// ---------------- segment GEMM helper, depth-4 prefetched (4 m-tiles x 16 cols) ----------------
struct PBuf { h16x8 a0, a1, a2, a3, b; };

__device__ __forceinline__ void pld(PBuf& p, const h16* __restrict__ Ap,
                                    const h16* __restrict__ Bp, int k){
  p.a0 = *reinterpret_cast<const h16x8*>(Ap + k);
  p.a1 = *reinterpret_cast<const h16x8*>(Ap + 16 * Hn + k);
  p.a2 = *reinterpret_cast<const h16x8*>(Ap + 32 * Hn + k);
  p.a3 = *reinterpret_cast<const h16x8*>(Ap + 48 * Hn + k);
  p.b  = *reinterpret_cast<const h16x8*>(Bp + k);
}
__device__ __forceinline__ void pmm(const PBuf& p, f32x4* acc){
  acc[0] = __builtin_amdgcn_mfma_f32_16x16x32_f16(p.a0, p.b, acc[0], 0, 0, 0);
  acc[1] = __builtin_amdgcn_mfma_f32_16x16x32_f16(p.a1, p.b, acc[1], 0, 0, 0);
  acc[2] = __builtin_amdgcn_mfma_f32_16x16x32_f16(p.a2, p.b, acc[2], 0, 0, 0);
  acc[3] = __builtin_amdgcn_mfma_f32_16x16x32_f16(p.a3, p.b, acc[3], 0, 0, 0);
}

// Ap pre-offset by la*Hn + q*8 (A row stride = Hn); Bp pre-offset by (n0+la)*bstr + bstart + q*8.
template<int NS>
__device__ __forceinline__ void gseg_pf(const h16* __restrict__ Ap,
                                        const h16* __restrict__ Bp, f32x4* acc){
  PBuf p0, p1, p2, p3;
  pld(p0, Ap, Bp, 0);
  pld(p1, Ap, Bp, 32);
  pld(p2, Ap, Bp, 64);
  pld(p3, Ap, Bp, 96);
  #pragma unroll 1
  for (int s = 0; s + 4 < NS; s += 4){
    pmm(p0, acc); pld(p0, Ap, Bp, (s + 4) * 32);
    pmm(p1, acc); pld(p1, Ap, Bp, (s + 5) * 32);
    pmm(p2, acc); pld(p2, Ap, Bp, (s + 6) * 32);
    pmm(p3, acc); pld(p3, Ap, Bp, (s + 7) * 32);
  }
  pmm(p0, acc); pmm(p1, acc); pmm(p2, acc); pmm(p3, acc);
}

// ---------------- kA: fused gates2(t) [blocks 0-63] + gates1(t+1) [blocks 64-127] ----------
// 256 threads, 4 waves; wave g accumulates gate g over the FULL flat K (same order as R7).
__global__ __launch_bounds__(256, 1) void kA(
    const h16* __restrict__ h1cur, const h16* __restrict__ h2prev, const h16* __restrict__ oh,
    h16* __restrict__ h1next, h16* __restrict__ h2cur, float* __restrict__ h2f,
    float* __restrict__ c1, float* __restrict__ c2,
    const h16* __restrict__ wih2, const h16* __restrict__ whh2, const h16* __restrict__ whh1,
    const float* __restrict__ bih2, const float* __restrict__ bhh2,
    const float* __restrict__ pre1_t, int mode)
{
  __shared__ float sg[4][64][17];
  int bid = blockIdx.x, tid = threadIdx.x;
  int g = tid >> 6, lane = tid & 63;
  int la = lane & 15, q = lane >> 4;
  bool is2 = (mode == 1) && (bid < 64);
  int jb = is2 ? bid : (mode == 1 ? bid - 64 : bid);
  int j0 = jb * 16;
  bool active = is2 || (pre1_t != nullptr);

  if (active){
    f32x4 acc[4];
    #pragma unroll
    for (int mi = 0; mi < 4; mi++) acc[mi] = (f32x4){0.f, 0.f, 0.f, 0.f};
    int n0 = g * 1024 + j0;
    if (is2){
      // flat K = [h1(t) | o(t-1) | h2(t-1)]; wih2 cols [0,2048), whh2 cols [0,1024)
      gseg_pf<32>(h1cur  + la * Hn + q * 8, wih2 + (size_t)(n0 + la) * 2048 + q * 8,        acc);
      gseg_pf<32>(oh     + la * Hn + q * 8, wih2 + (size_t)(n0 + la) * 2048 + 1024 + q * 8, acc);
      gseg_pf<32>(h2prev + la * Hn + q * 8, whh2 + (size_t)(n0 + la) * 1024 + q * 8,        acc);
    } else {
      gseg_pf<32>(h1cur  + la * Hn + q * 8, whh1 + (size_t)(n0 + la) * 1024 + q * 8,        acc);
    }
    #pragma unroll
    for (int mi = 0; mi < 4; mi++)
      #pragma unroll
      for (int r = 0; r < 4; r++)
        sg[g][mi * 16 + q * 4 + r][la] = acc[mi][r];
  }
  __syncthreads();
  if (active){
    for (int e = tid; e < 1024; e += 256){
      int row = e >> 4, col = e & 15, j = j0 + col;
      float gi = sg[0][row][col];
      float gf = sg[1][row][col];
      float gg = sg[2][row][col];
      float go = sg[3][row][col];
      if (is2){
        gi += bih2[j] + bhh2[j];
        gf += bih2[j + 1024] + bhh2[j + 1024];
        gg += bih2[j + 2048] + bhh2[j + 2048];
        go += bih2[j + 3072] + bhh2[j + 3072];
        float c_ = sigf(gf) * c2[row * Hn + j] + sigf(gi) * tanhf(gg);
        c2[row * Hn + j] = c_;
        float h_ = sigf(go) * tanhf(c_);
        h2cur[row * Hn + j] = (h16)h_;
        h2f[row * Hn + j] = h_;
      } else {
        const float* p = pre1_t + (size_t)row * Gn;   // includes bih1+bhh1
        gi += p[j]; gf += p[j + 1024]; gg += p[j + 2048]; go += p[j + 3072];
        float c_ = sigf(gf) * c1[row * Hn + j] + sigf(gi) * tanhf(gg);
        c1[row * Hn + j] = c_;
        h1next[row * Hn + j] = (h16)(sigf(go) * tanhf(c_));
      }
    }
  }
}

// ---------------- kB: e-dots (blocks 0-511) || hw = h2@Wcomb_b + bcomb (blocks 512-527) ----
__global__ __launch_bounds__(256, 2) void kB(
    const float* __restrict__ h2f, const h16* __restrict__ eph, const int* __restrict__ msk,
    float* __restrict__ ebuf,
    const h16* __restrict__ h2cur, const h16* __restrict__ wcomb, const float* __restrict__ bcomb,
    float* __restrict__ hwb)
{
  int bid = blockIdx.x, tid = threadIdx.x;
  int w = tid >> 6, lane = tid & 63;
  if (bid < 512){
    int wv = bid * 4 + w;           // 0..2047
    int b = wv >> 5;
    int l0 = (wv & 31) * 4;
    const f32x4* h2r = reinterpret_cast<const f32x4*>(h2f + b * Hn + lane * 16);
    f32x4 hv0 = h2r[0], hv1 = h2r[1], hv2 = h2r[2], hv3 = h2r[3];
    #pragma unroll
    for (int li = 0; li < 4; li++){
      int l = l0 + li;
      const h16x8* er = reinterpret_cast<const h16x8*>(eph + ((size_t)b * Ln + l) * Hn + lane * 16);
      h16x8 e0 = er[0], e1 = er[1];
      float acc = 0.f;
      #pragma unroll
      for (int i = 0; i < 4; i++) acc += hv0[i] * (float)e0[i];
      #pragma unroll
      for (int i = 0; i < 4; i++) acc += hv1[i] * (float)e0[4 + i];
      #pragma unroll
      for (int i = 0; i < 4; i++) acc += hv2[i] * (float)e1[i];
      #pragma unroll
      for (int i = 0; i < 4; i++) acc += hv3[i] * (float)e1[4 + i];
      for (int off = 32; off; off >>= 1) acc += __shfl_xor(acc, off);
      if (lane == 0) ebuf[b * Ln + l] = msk[b * Ln + l] ? -1e30f : acc;
    }
  } else {
    int hb = bid - 512;             // 0..15
    int la = lane & 15, q = lane >> 4;
    int n0 = hb * 64 + w * 16;
    f32x4 acc[4];
    #pragma unroll
    for (int mi = 0; mi < 4; mi++) acc[mi] = (f32x4){0.f, 0.f, 0.f, 0.f};
    gseg_pf<32>(h2cur + la * Hn + q * 8,
                wcomb + (size_t)(n0 + la) * (HEn + Hn) + HEn + q * 8, acc);
    float bs = bcomb[n0 + la];
    #pragma unroll
    for (int mi = 0; mi < 4; mi++)
      #pragma unroll
      for (int r = 0; r < 4; r++)
        hwb[(size_t)(mi * 16 + q * 4 + r) * Hn + n0 + la] = acc[mi][r] + bs;
  }
}

// ---------------- kC: softmax + o_t = tanh(sum_l alpha*enc_comb + hw) ----------------
// 256 blocks (b x quarter), 128 threads, shuffle-reduce softmax, 4 split acc chains.
__global__ __launch_bounds__(128, 4) void kC(
    int t, const float* __restrict__ ebuf,
    const h16* __restrict__ ecbh, const float* __restrict__ hwb,
    float* __restrict__ out, h16* __restrict__ oh)
{
  __shared__ float sb[Ln];
  __shared__ float red[4];
  int bid = blockIdx.x;
  int b = bid >> 2;
  int jq = (bid & 3) * 256;
  int tid = threadIdx.x;            // 0..127
  int w = tid >> 6;
  float e = ebuf[b * Ln + tid];
  float m = e;
  #pragma unroll
  for (int off = 32; off; off >>= 1) m = fmaxf(m, __shfl_xor(m, off));
  if ((tid & 63) == 0) red[w] = m;
  __syncthreads();
  m = fmaxf(red[0], red[1]);
  float ex = expf(e - m);
  sb[tid] = ex;
  float s = ex;
  #pragma unroll
  for (int off = 32; off; off >>= 1) s += __shfl_xor(s, off);
  if ((tid & 63) == 0) red[2 + w] = s;
  __syncthreads();
  float rinv = 1.f / (red[2] + red[3]);
  int j0 = jq + tid * 2;
  const h16* base = ecbh + (size_t)b * Ln * Hn + j0;
  float a0 = 0.f, a1 = 0.f, c0 = 0.f, c1 = 0.f;
  #pragma unroll 8
  for (int l = 0; l < Ln; l += 2){
    float al0 = sb[l], al1 = sb[l + 1];
    h16x2 p0 = *reinterpret_cast<const h16x2*>(base + (size_t)l * Hn);
    h16x2 p1 = *reinterpret_cast<const h16x2*>(base + (size_t)(l + 1) * Hn);
    a0 += al0 * (float)p0.x; a1 += al0 * (float)p0.y;
    c0 += al1 * (float)p1.x; c1 += al1 * (float)p1.y;
  }
  a0 = (a0 + c0) * rinv; a1 = (a1 + c1) * rinv;
  float2 hw2 = *reinterpret_cast<const float2*>(hwb + b * Hn + j0);   // bias included
  float o0 = tanhf(a0 + hw2.x);
  float o1 = tanhf(a1 + hw2.y);
  *reinterpret_cast<float2*>(out + ((size_t)t * Bn + b) * Hn + j0) = make_float2(o0, o1);
  h16x2 opk; opk.x = (h16)o0; opk.y = (h16)o1;
  *reinterpret_cast<h16x2*>(oh + b * Hn + j0) = opk;
}

// ---------------- host ----------------
extern "C" void kernel_launch(void* const* d_in, const int* in_sizes, int n_in,
                              void* d_out, int out_size, void* d_ws, size_t ws_size,
                              hipStream_t stream)
{
  const float* enc   = (const float*)d_in[0];
  const int*   msk   = (const int*)  d_in[1];
  const float* h1i   = (const float*)d_in[2];
  const float* c1i   = (const float*)d_in[3];
  const float* h2i   = (const float*)d_in[4];
  const float* c2i   = (const float*)d_in[5];
  const float* caps  = (const float*)d_in[6];
  const float* Wih1  = (const float*)d_in[7];
  const float* Whh1  = (const float*)d_in[8];
  const float* bih1  = (const float*)d_in[9];
  const float* bhh1  = (const float*)d_in[10];
  const float* Wih2  = (const float*)d_in[11];
  const float* Whh2  = (const float*)d_in[12];
  const float* bih2  = (const float*)d_in[13];
  const float* bhh2  = (const float*)d_in[14];
  const float* Watt  = (const float*)d_in[15];
  const float* batt  = (const float*)d_in[16];
  const float* Wcomb = (const float*)d_in[17];
  const float* bcomb = (const float*)d_in[18];
  float* out = (float*)d_out;

  char* p = (char*)d_ws;
  auto take = [&](size_t bytes){ char* r = p; p += (bytes + 255) & ~(size_t)255; return r; };
  float* pre1   = (float*)take((size_t)Tn * Bn * Gn * 4);          // 50.3 MB
  h16*   ench   = (h16*)take((size_t)Bn * Ln * HEn * 2);
  h16*   eph    = (h16*)take((size_t)Bn * Ln * Hn * 2);
  h16*   ecbh   = (h16*)take((size_t)Bn * Ln * Hn * 2);
  h16*   caph   = (h16*)take((size_t)Tn * Bn * En * 2);
  h16*   wih1h  = (h16*)take((size_t)Gn * En * 2);
  h16*   whh1h  = (h16*)take((size_t)Gn * Hn * 2);
  h16*   wih2h  = (h16*)take((size_t)Gn * 2 * Hn * 2);
  h16*   whh2h  = (h16*)take((size_t)Gn * Hn * 2);
  h16*   watth  = (h16*)take((size_t)Hn * HEn * 2);
  h16*   wcombh = (h16*)take((size_t)Hn * (HEn + Hn) * 2);
  h16*   h1b0   = (h16*)take((size_t)Bn * Hn * 2);
  h16*   h1b1   = (h16*)take((size_t)Bn * Hn * 2);
  h16*   h2b0   = (h16*)take((size_t)Bn * Hn * 2);
  h16*   h2b1   = (h16*)take((size_t)Bn * Hn * 2);
  h16*   oh     = (h16*)take((size_t)Bn * Hn * 2);
  float* c1     = (float*)take((size_t)Bn * Hn * 4);
  float* c2     = (float*)take((size_t)Bn * Hn * 4);
  float* h2f    = (float*)take((size_t)Bn * Hn * 4);
  float* ebuf   = (float*)take((size_t)Bn * Ln * 4);
  float* hwb    = (float*)take((size_t)Bn * Hn * 4);
  (void)ws_size; (void)n_in; (void)in_sizes; (void)out_size;

  auto cvt = [&](const float* src, void* dst, int n){
    int n2 = n / 2;
    int blocks = (n2 + 255) / 256; if (blocks > 2048) blocks = 2048;
    cvt2<<<blocks, 256, 0, stream>>>(src, (h16x2*)dst, n2);
  };
  cvt(enc,   ench,   Bn * Ln * HEn);
  cvt(caps,  caph,   Tn * Bn * En);
  cvt(Wih1,  wih1h,  Gn * En);
  cvt(Whh1,  whh1h,  Gn * Hn);
  cvt(Wih2,  wih2h,  Gn * 2 * Hn);
  cvt(Whh2,  whh2h,  Gn * Hn);
  cvt(Watt,  watth,  Hn * HEn);
  cvt(Wcomb, wcombh, Hn * (HEn + Hn));

  init_state<<<(Bn * Hn) / 256, 256, 0, stream>>>(h1i, c1i, h2i, c2i,
                                                  h1b0, c1, h2b0, c2, h2f, oh);

  // pre1 = captions @ Wih1^T + bih1 + bhh1   (3072 x 4096, K=512)
  gemm8<<<dim3((Tn * Bn) / 64, Gn / 128), 256, 0, stream>>>(
      caph, En, wih1h, En, bih1, bhh1, pre1, nullptr, Gn, En);
  // enc_proj = enc @ Watt^T + batt  (8192 x 1024, K=1024) -> fp16
  gemm8<<<dim3((Bn * Ln) / 64, Hn / 128), 256, 0, stream>>>(
      ench, HEn, watth, HEn, batt, nullptr, nullptr, eph, Hn, HEn);
  // enc_comb = enc @ Wcomb[:, :HE]^T  (8192 x 1024, K=1024) -> fp16
  gemm8<<<dim3((Bn * Ln) / 64, Hn / 128), 256, 0, stream>>>(
      ench, HEn, wcombh, HEn + Hn, nullptr, nullptr, nullptr, ecbh, Hn, HEn);

  // prime: gates1(0) -> h1(0) in h1b1 (h1 state for t lives in h1buf[(t+1)&1])
  kA<<<64, 256, 0, stream>>>(h1b0, h2b0, oh, h1b1, h2b1, h2f, c1, c2,
                             wih2h, whh2h, whh1h, bih2, bhh2, pre1, /*mode=*/0);

  h16* h1buf[2] = { h1b0, h1b1 };
  h16* h2buf[2] = { h2b0, h2b1 };
  for (int t = 0; t < Tn; t++){
    h16* h1cur  = h1buf[(t + 1) & 1];
    h16* h1next = h1buf[t & 1];
    h16* h2prev = h2buf[t & 1];
    h16* h2cur  = h2buf[(t + 1) & 1];
    const float* pre1_t = (t + 1 < Tn) ? (pre1 + (size_t)(t + 1) * Bn * Gn) : nullptr;
    kA<<<128, 256, 0, stream>>>(h1cur, h2prev, oh, h1next, h2cur, h2f, c1, c2,
                                wih2h, whh2h, whh1h, bih2, bhh2, pre1_t, /*mode=*/1);
    kB<<<528, 256, 0, stream>>>(h2f, eph, msk, ebuf, h2cur, wcombh, bcomb, hwb);
    kC<<<256, 128, 0, stream>>>(t, ebuf, ecbh, hwb, out, oh);
  }
}